// Round 3
// baseline (610.722 us; speedup 1.0000x reference)
//
#include <hip/hip_runtime.h>

// x [4,2048,4096] f32, dna [6] f32, bias [4096] f32, hd [4096,4096] i32,
// out [4,2048,4096] f32. Internally W and X are cast to bf16 for the MFMA GEMM.
#define M_DIM 4096
#define K_DIM 4096
#define NR_DIM 8192
#define TOTAL_ELEMS (M_DIM * K_DIM)

typedef unsigned short u16;
typedef unsigned int u32;
typedef __bf16 bf16x8 __attribute__((ext_vector_type(8)));
typedef float f32x4 __attribute__((ext_vector_type(4)));
typedef u16 u16x8 __attribute__((ext_vector_type(8)));

__device__ __forceinline__ u16 f2b(float f) {
    u32 v;
    __builtin_memcpy(&v, &f, sizeof(v));
    v += 0x7FFFu + ((v >> 16) & 1u);  // round-to-nearest-even
    return (u16)(v >> 16);
}

// Inline |sin|,|cos| via Cody-Waite + minimax polys. Signs are irrelevant
// downstream (fabs), so quadrant handling is a parity swap only.
__device__ __forceinline__ void abs_sincos(float ang, float* s, float* c) {
    float q = rintf(ang * 0.636619772f);
    float r1 = fmaf(q, -1.57079637e+00f, ang);
    float r = fmaf(q, 4.37113883e-08f, r1);
    float r2 = r * r;
    float ts = fmaf(r2, -1.9840874e-04f, 8.3333310e-03f);
    ts = fmaf(r2, ts, -1.6666667e-01f);
    float sp = fmaf(r * r2, ts, r);
    float tc = fmaf(r2, -1.3888378e-03f, 4.1666638e-02f);
    tc = fmaf(r2, tc, -5.0e-01f);
    float cp = fmaf(r2, tc, 1.0f);
    bool sw = (((int)q) & 1) != 0;
    *s = sw ? cp : sp;
    *c = sw ? sp : cp;
}

// FAST path, valid when a==b==1, n1==n2==n3==0.5 (the actual dna):
// r = 1 / (sqrt|cos| + sqrt|sin|)^2. base in [1, 1.68] — no singularity.
__device__ __forceinline__ float compute_r_fast(int d, float c_ang) {
    float s, c;
    abs_sincos((float)d * c_ang, &s, &c);
    float base = __builtin_amdgcn_sqrtf(fabsf(c)) + __builtin_amdgcn_sqrtf(fabsf(s));
    return __builtin_amdgcn_rcpf(base * base);
}

// GENERIC path for arbitrary dna (powf etc.) — wave-uniform-selected, cold.
__device__ __noinline__ float compute_r_gen(int d, float c_ang, float inv_a,
                                            float inv_b, float n2, float n3, float e) {
    float s, c;
    abs_sincos((float)d * c_ang, &s, &c);
    float ca = fabsf(c) * fabsf(inv_a);
    float sb = fabsf(s) * fabsf(inv_b);
    float t1 = (n2 == 0.5f) ? sqrtf(ca) : ((n2 == 1.0f) ? ca : powf(ca, n2));
    float t2 = (n3 == 0.5f) ? sqrtf(sb) : ((n3 == 1.0f) ? sb : powf(sb, n3));
    float base = t1 + t2;
    if (e == -2.0f) { float ib = __builtin_amdgcn_rcpf(base); return ib * ib; }
    if (e == -1.0f) return __builtin_amdgcn_rcpf(base);
    return powf(base, e);
}

__device__ __forceinline__ bool dna_is_fast(const float* p) {
    return (p[1] == 1.0f) & (p[2] == 1.0f) & (p[3] == 0.5f) &
           (p[4] == 0.5f) & (p[5] == 0.5f);
}

// Kernel 1: sum / sum-of-squares of r (hd is a bijection onto [0,2^24)).
__global__ void __launch_bounds__(256) reduce_kernel(const float* __restrict__ dna,
                                                     double* __restrict__ sums) {
    float p[6];
#pragma unroll
    for (int i = 0; i < 6; i++) p[i] = dna[i];
    float c_ang = (float)((double)p[0] * 6.283185307179586 / 67108864.0);

    double s = 0.0, s2 = 0.0;
    int idx = blockIdx.x * blockDim.x + threadIdx.x;
    int stride = gridDim.x * blockDim.x;
    if (dna_is_fast(p)) {
        for (int d = idx; d < TOTAL_ELEMS; d += stride) {
            float r = compute_r_fast(d, c_ang);
            s += (double)r;
            s2 += (double)r * (double)r;
        }
    } else {
        float inv_a = 1.0f / p[1], inv_b = 1.0f / p[2], e = -1.0f / p[3];
        for (int d = idx; d < TOTAL_ELEMS; d += stride) {
            float r = compute_r_gen(d, c_ang, inv_a, inv_b, p[4], p[5], e);
            s += (double)r;
            s2 += (double)r * (double)r;
        }
    }
#pragma unroll
    for (int off = 32; off > 0; off >>= 1) {
        s += __shfl_down(s, off);
        s2 += __shfl_down(s2, off);
    }
    __shared__ double ls[4], ls2[4];
    int lane = threadIdx.x & 63, w = threadIdx.x >> 6;
    if (lane == 0) { ls[w] = s; ls2[w] = s2; }
    __syncthreads();
    if (threadIdx.x == 0) {
        atomicAdd(&sums[0], ls[0] + ls[1] + ls[2] + ls[3]);
        atomicAdd(&sums[1], ls2[0] + ls2[1] + ls2[2] + ls2[3]);
    }
}

// Kernel 2: W[m,k] = (r - mean)/(std_ddof1 + 1e-9) * (1/sqrt(K)), stored bf16.
__global__ void __launch_bounds__(256) build_w_kernel(const int* __restrict__ hd,
                                                      const float* __restrict__ dna,
                                                      const double* __restrict__ sums,
                                                      u16* __restrict__ W) {
    float p[6];
#pragma unroll
    for (int i = 0; i < 6; i++) p[i] = dna[i];
    float c_ang = (float)((double)p[0] * 6.283185307179586 / 67108864.0);

    const double cnt = (double)TOTAL_ELEMS;
    double sum = sums[0], sumsq = sums[1];
    float meanf = (float)(sum / cnt);
    float stdf = (float)sqrt((sumsq - sum * sum / cnt) / (cnt - 1.0));
    float sc = 0.015625f / (stdf + 1e-9f);  // fold 1/sqrt(4096)

    int idx = blockIdx.x * blockDim.x + threadIdx.x;
    int stride = gridDim.x * blockDim.x;
    if (dna_is_fast(p)) {
        for (int i = idx * 4; i < TOTAL_ELEMS; i += stride * 4) {
            int4 d4 = *(const int4*)(hd + i);
            ushort4 o;
            o.x = f2b((compute_r_fast(d4.x, c_ang) - meanf) * sc);
            o.y = f2b((compute_r_fast(d4.y, c_ang) - meanf) * sc);
            o.z = f2b((compute_r_fast(d4.z, c_ang) - meanf) * sc);
            o.w = f2b((compute_r_fast(d4.w, c_ang) - meanf) * sc);
            *(ushort4*)(W + i) = o;
        }
    } else {
        float inv_a = 1.0f / p[1], inv_b = 1.0f / p[2], e = -1.0f / p[3];
        for (int i = idx * 4; i < TOTAL_ELEMS; i += stride * 4) {
            int4 d4 = *(const int4*)(hd + i);
            ushort4 o;
            o.x = f2b((compute_r_gen(d4.x, c_ang, inv_a, inv_b, p[4], p[5], e) - meanf) * sc);
            o.y = f2b((compute_r_gen(d4.y, c_ang, inv_a, inv_b, p[4], p[5], e) - meanf) * sc);
            o.z = f2b((compute_r_gen(d4.z, c_ang, inv_a, inv_b, p[4], p[5], e) - meanf) * sc);
            o.w = f2b((compute_r_gen(d4.w, c_ang, inv_a, inv_b, p[4], p[5], e) - meanf) * sc);
            *(ushort4*)(W + i) = o;
        }
    }
}

// Kernel 3: x f32 -> bf16 (8 elements/thread).
__global__ void __launch_bounds__(256) convert_x_kernel(const float* __restrict__ x,
                                                        u16* __restrict__ xb) {
    int i = (blockIdx.x * blockDim.x + threadIdx.x) * 8;
    const float4* xv = (const float4*)(x + i);
    float4 a = xv[0], b = xv[1];
    u16x8 o;
    o[0] = f2b(a.x); o[1] = f2b(a.y); o[2] = f2b(a.z); o[3] = f2b(a.w);
    o[4] = f2b(b.x); o[5] = f2b(b.y); o[6] = f2b(b.z); o[7] = f2b(b.w);
    *(u16x8*)(xb + i) = o;
}

// ---------------- GEMM: C[NR,M] = X[NR,K] * W[M,K]^T -----------------------
// Round 3: one-phase-ahead REGISTER PREFETCH of fragments. Rounds 1-2 showed
// the 8-phase skeleton alone is null (MfmaUtil stuck at 36%): each phase's
// ds_reads are issued just before the barrier and waited just after, so the
// LDS service burst (~600-1000 cyc/phase/CU) serializes with the MFMA cluster
// (~620 cyc) instead of overlapping. Now phase p issues phase p+1's af reads
// (ping-pong banks af_a/af_b) and fresh bfr reads are issued first in-phase;
// NO manual lgkm drain — the compiler's dependency-driven counted lgkmcnt
// gates each MFMA on exactly the reads it needs, so MFMA starts as soon as
// its operands land while later reads are still being serviced.
// Register budget: af_a+af_b+bfr = 12 frags (48 VGPR) + 128 acc ≈ 252/wave,
// under the 256 cliff for 2 waves/SIMD (enforced by __launch_bounds__(512,2)).
//
// Safety (stage map unchanged: P1->(t+1).Ab, P2->(t+1).Bb, P3->(t+2).Aa,
// P4->(t+2).Ba; vm6 at P2/P4 end; 2 barriers/phase):
//  RAW (read-issue vs stage-landing), steady state:
//   (t).Aa h0 issued t-1.P4: staged t-2.P3, landed by t-1.P2-end vm6. OK
//   (t).Aa h1 issued t.P1:   same slot. OK
//   (t).Ba    issued t.P1:   staged t-2.P4, landed by t-1.P4-end vm6. OK
//   (t).Ab h0 issued t.P2:   staged t-1.P1, landed by t-1.P4-end vm6. OK
//   (t).Ab h1 issued t.P3:   same slot. OK
//   (t).Bb    issued t.P3:   staged t-1.P2, landed by t.P2-end vm6. OK
//  Prologue: vm6 (not vm8) so pairs 1-3 (0.Aa,0.Ba,0.Ab) are landed before
//   t0.P2's prefetch of 0.Ab; 0.Bb/1.Aa/1.Ba covered by t0.P2/P4 vm6.
//  WAW (stage overwriting a read slot): every slot's last consuming MFMA
//   carries a compiler lgkm wait, and >=1 barrier separates that MFMA from
//   the overwriting stage (per-slot windows re-derived this round).
//  Tail stages CLAMPED (re-stage tile 63) so vmcnt stays steady-state exact;
//  the final P4 prefetch reads a dead bank (harmless).
#define BM 256
#define BN 256
#define BK 64

__device__ __forceinline__ void gld_lds16(const u16* g, u16* l) {
    __builtin_amdgcn_global_load_lds(
        (const __attribute__((address_space(1))) void*)g,
        (__attribute__((address_space(3))) void*)l,
        16, 0, 0);
}

#define FENCE asm volatile("" ::: "memory")
#define WAIT_VM6 asm volatile("s_waitcnt vmcnt(6)" ::: "memory")

// Issue 4 A-fragment ds_reads into bank `dst` (rows h*64..h*64+63 of this
// wave's 128-row half; k-slice ks).
#define ISSUE_AF(dst, bufv, ks, h)                                            \
    _Pragma("unroll") for (int m = 0; m < 4; ++m) {                           \
        int row = wr * 128 + ((h) * 4 + m) * 16 + lrow;                       \
        dst[m] = *(const bf16x8*)(&sA[bufv][ks][row * 32 + oA]);              \
    }

// Issue 4 B-fragment ds_reads (this wave's 64-col quarter; k-slice ks).
#define ISSUE_BF(dst, bufv, ks)                                               \
    _Pragma("unroll") for (int n = 0; n < 4; ++n) {                           \
        int row = wc * 64 + n * 16 + lrow;                                    \
        dst[n] = *(const bf16x8*)(&sB[bufv][ks][row * 32 + oA]);              \
    }

#define MFMA_HALF(h, afb, bfb)                                                \
    __builtin_amdgcn_s_setprio(1);                                            \
    _Pragma("unroll") for (int m = 0; m < 4; ++m)                             \
        _Pragma("unroll") for (int n = 0; n < 4; ++n)                         \
            acc[(h) * 4 + m][n] = __builtin_amdgcn_mfma_f32_16x16x32_bf16(    \
                afb[m], bfb[n], acc[(h) * 4 + m][n], 0, 0, 0);                \
    __builtin_amdgcn_s_setprio(0)

__global__ void __launch_bounds__(512, 2) gemm_kernel(const u16* __restrict__ A,
                                                      const u16* __restrict__ B,
                                                      const float* __restrict__ bias,
                                                      float* __restrict__ C) {
    __shared__ __align__(16) u16 sA[2][2][BM * 32];  // 64 KB
    __shared__ __align__(16) u16 sB[2][2][BN * 32];  // 64 KB

    const int tid = threadIdx.x;
    const int lane = tid & 63;
    const int wave = tid >> 6;  // 0..7
    const int wr = wave >> 2;   // 0..1 -> 128-row half of C-tile (NR dim)
    const int wc = wave & 3;    // 0..3 -> 64-col quarter of C-tile (M dim)
    const int lrow = lane & 15;
    const int lq = lane >> 4;
    const int oA = ((lq ^ ((lrow >> 1) & 3)) << 3);  // swizzled octet, u16 units

    // XCD-aware bijective swizzle: 512 wg, 8 XCDs, 64 wg per XCD chunk.
    const int flat = blockIdx.y * 16 + blockIdx.x;
    const int swz = (flat & 7) * 64 + (flat >> 3);
    const int bx = swz & 15;   // M tile
    const int by = swz >> 4;   // NR tile
    const int i0 = by * BM;
    const int j0 = bx * BN;

    // Staging: thread writes LDS linearly at 16*tid and 16*(tid+512); the
    // matching slot position is row=(L>>2), stored octet=(L&3); source octet
    // pre-swizzled. olog is identical for both loads (row1=row0+128, 128/2%4==0).
    const int srow0 = tid >> 2;  // 0..127
    const int olog = (tid & 3) ^ ((srow0 >> 1) & 3);
    const int aoff0 = (i0 + srow0) * K_DIM + olog * 8;
    const int aoff1 = aoff0 + 128 * K_DIM;
    const int boff0 = (j0 + srow0) * K_DIM + olog * 8;
    const int boff1 = boff0 + 128 * K_DIM;
    const int lds_l0 = tid * 8;          // u16 units
    const int lds_l1 = (tid + 512) * 8;

    auto stage = [&](const u16* base, int off0, int off1, u16* slot, int kb) {
        gld_lds16(base + off0 + kb, slot + lds_l0);
        gld_lds16(base + off1 + kb, slot + lds_l1);
    };

    const f32x4 vzero = {0.f, 0.f, 0.f, 0.f};
    f32x4 acc[8][4];
#pragma unroll
    for (int a = 0; a < 8; a++)
#pragma unroll
        for (int b = 0; b < 4; b++) acc[a][b] = vzero;

    // Prologue: 6 slot stages (12 loads); vm6 -> first 3 pairs landed
    // (0.Aa, 0.Ba, 0.Ab — all slots whose reads issue before t0.P2-end).
    stage(A, aoff0, aoff1, sA[0][0], 0);    // 0.Aalpha
    stage(B, boff0, boff1, sB[0][0], 0);    // 0.Balpha
    stage(A, aoff0, aoff1, sA[0][1], 32);   // 0.Abeta
    stage(B, boff0, boff1, sB[0][1], 32);   // 0.Bbeta
    stage(A, aoff0, aoff1, sA[1][0], 64);   // 1.Aalpha
    stage(B, boff0, boff1, sB[1][0], 64);   // 1.Balpha
    WAIT_VM6;
    FENCE;
    __builtin_amdgcn_s_barrier();

    bf16x8 af_a[4], af_b[4], bfr[4];
    // Pre-loop: issue t0.P1's A fragments (bank a).
    ISSUE_AF(af_a, 0, 0, 0);
    FENCE;

    for (int kt = 0; kt < K_DIM / BK; ++kt) {
        const int bufv = kt & 1;
        const int kb1 = (kt + 1 < 64 ? kt + 1 : 63) * 64 + 32;  // clamped tail
        const int kb2 = (kt + 2 < 64 ? kt + 2 : 63) * 64;

        // ---- phase 1: MFMA(h0,ks0) on af_a; issue bfr(ks0) + af_b for P2 ----
        ISSUE_BF(bfr, bufv, 0);
        ISSUE_AF(af_b, bufv, 0, 1);
        stage(A, aoff0, aoff1, sA[bufv ^ 1][1], kb1);
        FENCE;
        __builtin_amdgcn_s_barrier();
        MFMA_HALF(0, af_a, bfr);
        FENCE;
        __builtin_amdgcn_s_barrier();

        // ---- phase 2: MFMA(h1,ks0) on af_b; issue af_a for P3 ----
        ISSUE_AF(af_a, bufv, 1, 0);
        stage(B, boff0, boff1, sB[bufv ^ 1][1], kb1);
        FENCE;
        __builtin_amdgcn_s_barrier();
        MFMA_HALF(1, af_b, bfr);
        WAIT_VM6;
        FENCE;
        __builtin_amdgcn_s_barrier();

        // ---- phase 3: MFMA(h0,ks1) on af_a; issue bfr(ks1) + af_b for P4 ----
        ISSUE_BF(bfr, bufv, 1);
        ISSUE_AF(af_b, bufv, 1, 1);
        stage(A, aoff0, aoff1, sA[bufv][0], kb2);
        FENCE;
        __builtin_amdgcn_s_barrier();
        MFMA_HALF(0, af_a, bfr);
        FENCE;
        __builtin_amdgcn_s_barrier();

        // ---- phase 4: MFMA(h1,ks1) on af_b; issue af_a for next-tile P1 ----
        ISSUE_AF(af_a, bufv ^ 1, 0, 0);
        stage(B, boff0, boff1, sB[bufv][0], kb2);
        FENCE;
        __builtin_amdgcn_s_barrier();
        MFMA_HALF(1, af_b, bfr);
        WAIT_VM6;
        FENCE;
        __builtin_amdgcn_s_barrier();
    }

    // Epilogue: same fragment->C mapping as the harness-verified 128^2 kernel.
#pragma unroll
    for (int ni = 0; ni < 4; ++ni) {
        long j = j0 + wc * 64 + ni * 16 + lrow;
        float bv = bias[j];
#pragma unroll
        for (int mi = 0; mi < 8; ++mi) {
            long ib = i0 + wr * 128 + mi * 16 + lq * 4;
#pragma unroll
            for (int r = 0; r < 4; ++r) {
                C[(ib + r) * M_DIM + j] = acc[mi][ni][r] + bv;
            }
        }
    }
}

extern "C" void kernel_launch(void* const* d_in, const int* in_sizes, int n_in,
                              void* d_out, int out_size, void* d_ws, size_t ws_size,
                              hipStream_t stream) {
    const float* x = (const float*)d_in[0];
    const float* dna = (const float*)d_in[1];
    const float* bias = (const float*)d_in[2];
    const int* hd = (const int*)d_in[3];
    float* out = (float*)d_out;

    double* sums = (double*)d_ws;                                   // 16 B
    u16* W = (u16*)((char*)d_ws + 256);                             // 32 MB bf16
    u16* Xb = (u16*)((char*)d_ws + 256 + (size_t)TOTAL_ELEMS * 2);  // 64 MB bf16

    hipMemsetAsync(d_ws, 0, 256, stream);
    reduce_kernel<<<dim3(1024), dim3(256), 0, stream>>>(dna, sums);
    build_w_kernel<<<dim3(2048), dim3(256), 0, stream>>>(hd, dna, sums, W);
    convert_x_kernel<<<dim3((NR_DIM * K_DIM) / (256 * 8)), dim3(256), 0, stream>>>(x, Xb);
    gemm_kernel<<<dim3(M_DIM / BN, NR_DIM / BM), dim3(512), 0, stream>>>(Xb, W, bias, out);
}

// Round 4
// 574.862 us; speedup vs baseline: 1.0624x; 1.0624x over previous
//
#include <hip/hip_runtime.h>

// x [4,2048,4096] f32, dna [6] f32, bias [4096] f32, hd [4096,4096] i32,
// out [4,2048,4096] f32. Internally W and X are cast to bf16 for the MFMA GEMM.
#define M_DIM 4096
#define K_DIM 4096
#define NR_DIM 8192
#define TOTAL_ELEMS (M_DIM * K_DIM)

typedef unsigned short u16;
typedef unsigned int u32;
typedef __bf16 bf16x8 __attribute__((ext_vector_type(8)));
typedef float f32x4 __attribute__((ext_vector_type(4)));
typedef u16 u16x8 __attribute__((ext_vector_type(8)));

__device__ __forceinline__ u16 f2b(float f) {
    u32 v;
    __builtin_memcpy(&v, &f, sizeof(v));
    v += 0x7FFFu + ((v >> 16) & 1u);  // round-to-nearest-even
    return (u16)(v >> 16);
}

// Inline |sin|,|cos| via Cody-Waite + minimax polys. Signs are irrelevant
// downstream (fabs), so quadrant handling is a parity swap only.
__device__ __forceinline__ void abs_sincos(float ang, float* s, float* c) {
    float q = rintf(ang * 0.636619772f);
    float r1 = fmaf(q, -1.57079637e+00f, ang);
    float r = fmaf(q, 4.37113883e-08f, r1);
    float r2 = r * r;
    float ts = fmaf(r2, -1.9840874e-04f, 8.3333310e-03f);
    ts = fmaf(r2, ts, -1.6666667e-01f);
    float sp = fmaf(r * r2, ts, r);
    float tc = fmaf(r2, -1.3888378e-03f, 4.1666638e-02f);
    tc = fmaf(r2, tc, -5.0e-01f);
    float cp = fmaf(r2, tc, 1.0f);
    bool sw = (((int)q) & 1) != 0;
    *s = sw ? cp : sp;
    *c = sw ? sp : cp;
}

// FAST path, valid when a==b==1, n1==n2==n3==0.5 (the actual dna):
// r = 1 / (sqrt|cos| + sqrt|sin|)^2. base in [1, 1.68] — no singularity.
__device__ __forceinline__ float compute_r_fast(int d, float c_ang) {
    float s, c;
    abs_sincos((float)d * c_ang, &s, &c);
    float base = __builtin_amdgcn_sqrtf(fabsf(c)) + __builtin_amdgcn_sqrtf(fabsf(s));
    return __builtin_amdgcn_rcpf(base * base);
}

// GENERIC path for arbitrary dna (powf etc.) — wave-uniform-selected, cold.
__device__ __noinline__ float compute_r_gen(int d, float c_ang, float inv_a,
                                            float inv_b, float n2, float n3, float e) {
    float s, c;
    abs_sincos((float)d * c_ang, &s, &c);
    float ca = fabsf(c) * fabsf(inv_a);
    float sb = fabsf(s) * fabsf(inv_b);
    float t1 = (n2 == 0.5f) ? sqrtf(ca) : ((n2 == 1.0f) ? ca : powf(ca, n2));
    float t2 = (n3 == 0.5f) ? sqrtf(sb) : ((n3 == 1.0f) ? sb : powf(sb, n3));
    float base = t1 + t2;
    if (e == -2.0f) { float ib = __builtin_amdgcn_rcpf(base); return ib * ib; }
    if (e == -1.0f) return __builtin_amdgcn_rcpf(base);
    return powf(base, e);
}

__device__ __forceinline__ bool dna_is_fast(const float* p) {
    return (p[1] == 1.0f) & (p[2] == 1.0f) & (p[3] == 0.5f) &
           (p[4] == 0.5f) & (p[5] == 0.5f);
}

// Kernel 1: sum / sum-of-squares of r (hd is a bijection onto [0,2^24)).
__global__ void __launch_bounds__(256) reduce_kernel(const float* __restrict__ dna,
                                                     double* __restrict__ sums) {
    float p[6];
#pragma unroll
    for (int i = 0; i < 6; i++) p[i] = dna[i];
    float c_ang = (float)((double)p[0] * 6.283185307179586 / 67108864.0);

    double s = 0.0, s2 = 0.0;
    int idx = blockIdx.x * blockDim.x + threadIdx.x;
    int stride = gridDim.x * blockDim.x;
    if (dna_is_fast(p)) {
        for (int d = idx; d < TOTAL_ELEMS; d += stride) {
            float r = compute_r_fast(d, c_ang);
            s += (double)r;
            s2 += (double)r * (double)r;
        }
    } else {
        float inv_a = 1.0f / p[1], inv_b = 1.0f / p[2], e = -1.0f / p[3];
        for (int d = idx; d < TOTAL_ELEMS; d += stride) {
            float r = compute_r_gen(d, c_ang, inv_a, inv_b, p[4], p[5], e);
            s += (double)r;
            s2 += (double)r * (double)r;
        }
    }
#pragma unroll
    for (int off = 32; off > 0; off >>= 1) {
        s += __shfl_down(s, off);
        s2 += __shfl_down(s2, off);
    }
    __shared__ double ls[4], ls2[4];
    int lane = threadIdx.x & 63, w = threadIdx.x >> 6;
    if (lane == 0) { ls[w] = s; ls2[w] = s2; }
    __syncthreads();
    if (threadIdx.x == 0) {
        atomicAdd(&sums[0], ls[0] + ls[1] + ls[2] + ls[3]);
        atomicAdd(&sums[1], ls2[0] + ls2[1] + ls2[2] + ls2[3]);
    }
}

// Kernel 2: W[m,k] = (r - mean)/(std_ddof1 + 1e-9) * (1/sqrt(K)), stored bf16.
__global__ void __launch_bounds__(256) build_w_kernel(const int* __restrict__ hd,
                                                      const float* __restrict__ dna,
                                                      const double* __restrict__ sums,
                                                      u16* __restrict__ W) {
    float p[6];
#pragma unroll
    for (int i = 0; i < 6; i++) p[i] = dna[i];
    float c_ang = (float)((double)p[0] * 6.283185307179586 / 67108864.0);

    const double cnt = (double)TOTAL_ELEMS;
    double sum = sums[0], sumsq = sums[1];
    float meanf = (float)(sum / cnt);
    float stdf = (float)sqrt((sumsq - sum * sum / cnt) / (cnt - 1.0));
    float sc = 0.015625f / (stdf + 1e-9f);  // fold 1/sqrt(4096)

    int idx = blockIdx.x * blockDim.x + threadIdx.x;
    int stride = gridDim.x * blockDim.x;
    if (dna_is_fast(p)) {
        for (int i = idx * 4; i < TOTAL_ELEMS; i += stride * 4) {
            int4 d4 = *(const int4*)(hd + i);
            ushort4 o;
            o.x = f2b((compute_r_fast(d4.x, c_ang) - meanf) * sc);
            o.y = f2b((compute_r_fast(d4.y, c_ang) - meanf) * sc);
            o.z = f2b((compute_r_fast(d4.z, c_ang) - meanf) * sc);
            o.w = f2b((compute_r_fast(d4.w, c_ang) - meanf) * sc);
            *(ushort4*)(W + i) = o;
        }
    } else {
        float inv_a = 1.0f / p[1], inv_b = 1.0f / p[2], e = -1.0f / p[3];
        for (int i = idx * 4; i < TOTAL_ELEMS; i += stride * 4) {
            int4 d4 = *(const int4*)(hd + i);
            ushort4 o;
            o.x = f2b((compute_r_gen(d4.x, c_ang, inv_a, inv_b, p[4], p[5], e) - meanf) * sc);
            o.y = f2b((compute_r_gen(d4.y, c_ang, inv_a, inv_b, p[4], p[5], e) - meanf) * sc);
            o.z = f2b((compute_r_gen(d4.z, c_ang, inv_a, inv_b, p[4], p[5], e) - meanf) * sc);
            o.w = f2b((compute_r_gen(d4.w, c_ang, inv_a, inv_b, p[4], p[5], e) - meanf) * sc);
            *(ushort4*)(W + i) = o;
        }
    }
}

// Kernel 3: x f32 -> bf16 (8 elements/thread).
__global__ void __launch_bounds__(256) convert_x_kernel(const float* __restrict__ x,
                                                        u16* __restrict__ xb) {
    int i = (blockIdx.x * blockDim.x + threadIdx.x) * 8;
    const float4* xv = (const float4*)(x + i);
    float4 a = xv[0], b = xv[1];
    u16x8 o;
    o[0] = f2b(a.x); o[1] = f2b(a.y); o[2] = f2b(a.z); o[3] = f2b(a.w);
    o[4] = f2b(b.x); o[5] = f2b(b.y); o[6] = f2b(b.z); o[7] = f2b(b.w);
    *(u16x8*)(xb + i) = o;
}

// ---------------- GEMM: C[NR,M] = X[NR,K] * W[M,K]^T -----------------------
// Round 4: FULL one-phase-ahead prefetch (all four operand banks double-
// buffered in registers) + loads-before-MFMA in EVERY phase + ONE barrier per
// phase. Mechanism (rounds 1-3 post-mortems): MFMA issue occupies the wave
// while the matrix pipe drains (~620 cyc/SIMD per phase), so any ds_read
// placed after the cluster cannot overlap it. Every phase now has, in program
// order: [issue next phase's ds_reads | stage DMA | sched_barrier(0) |
// MFMA cluster (operands loaded LAST phase; compiler emits counted lgkmcnt
// for true deps only) | vm-wait (P1/P3) | barrier]. The LDS unit services the
// prefetch burst while the matrix pipe drains. sched_barrier(0) stops the
// compiler hoisting the register-only MFMA cluster above the loads (rule:
// hipcc hoists MFMA past asm waits).
//
// Operand banks (rule #20 — all statically indexed):
//   afA/afB: A-frag ping-pong. bfA: B ks0 (consumed P1+P2). bfB: B ks1 (P3+P4).
//   pre-P1 (prev P4): afA<-(buf,ks0,h0), bfA<-(buf,ks0)
//   P1: issue afB<-(buf,ks0,h1);            MFMA(h0: afA,bfA); stage A->(t+1).Ab; vm6
//   P2: issue afA<-(buf,ks1,h0), bfB<-(buf,ks1); MFMA(h1: afB,bfA); stage B->(t+1).Bb
//   P3: issue afB<-(buf,ks1,h1);            MFMA(h0: afA,bfB); stage A->(t+2).Aa; vm6
//   P4: issue afA<-(buf^1,ks0,h0), bfA<-(buf^1,ks0); MFMA(h1: afB,bfB); stage B->(t+2).Ba
//
// Safety proofs (single end-of-phase barrier; vmcnt is PER-WAVE, so every
// vm-wait is placed BEFORE a barrier and the protected reads AFTER it —
// collective by barrier semantics):
//  RAW (prefetch-issue vs stage-landing):
//   P2 reads t.Ab(staged t-1.P1), t.Bb(t-1.P2): vm6 at t.P1-end leaves newest
//     6 loads {t.P1, t-1.P4, t-1.P3 stages} outstanding => t-1.P2 and older
//     landed. Barrier follows. OK
//   P4 reads (t+1).Aa(t-1.P3), (t+1).Ba(t-1.P4): vm6 at t.P3-end leaves
//     {t.P3,t.P2,t.P1} => t-1.P4 and older landed. OK
//   P1 reads t.Aa(t-2.P3): covered by t-1.P3-end vm6. OK
//   P3 reads t.Ab(t-1.P1): covered by t.P1-end vm6. OK
//  WAW (stage overwriting a slot still being read): each slot's last ds_reads
//   are consumed by an MFMA (compiler lgkm) before the reader's phase-end
//   barrier; the overwriting stage issues only after ALL waves pass that
//   barrier. Verified for all 4 targets (Aa@P3, Ba@P4, Ab@P1, Bb@P2).
//  Prologue: 6 stages, vm4 (0.Aa,0.Ba landed), barrier, then pre-loop issue.
//   t0.P1-end vm6: 14 loads issued => stages 1-4 landed => covers t0.P2. OK
//  Tail: stages CLAMPED (tile 63) into dead/drained slots; final prefetches
//   read dead banks (harmless). vmcnt stays steady-state exact.
#define BM 256
#define BN 256
#define BK 64

__device__ __forceinline__ void gld_lds16(const u16* g, u16* l) {
    __builtin_amdgcn_global_load_lds(
        (const __attribute__((address_space(1))) void*)g,
        (__attribute__((address_space(3))) void*)l,
        16, 0, 0);
}

#define FENCE asm volatile("" ::: "memory")
#define WAIT_VM6 asm volatile("s_waitcnt vmcnt(6)" ::: "memory")
#define WAIT_VM4 asm volatile("s_waitcnt vmcnt(4)" ::: "memory")
#define SB0 __builtin_amdgcn_sched_barrier(0)

// Issue 4 A-fragment ds_reads into bank `dst` (rows h*64..h*64+63 of this
// wave's 128-row half; k-slice ks of buffer bufv).
#define ISSUE_A(dst, bufv, ks, h)                                             \
    _Pragma("unroll") for (int m = 0; m < 4; ++m) {                           \
        int row = wr * 128 + ((h) * 4 + m) * 16 + lrow;                       \
        dst[m] = *(const bf16x8*)(&sA[bufv][ks][row * 32 + oA]);              \
    }

// Issue 4 B-fragment ds_reads into bank `dst` (this wave's 64-col quarter).
#define ISSUE_B(dst, bufv, ks)                                                \
    _Pragma("unroll") for (int n = 0; n < 4; ++n) {                           \
        int row = wc * 64 + n * 16 + lrow;                                    \
        dst[n] = *(const bf16x8*)(&sB[bufv][ks][row * 32 + oA]);              \
    }

#define MFMA_HALF(h, afb, bfb)                                                \
    __builtin_amdgcn_s_setprio(1);                                            \
    _Pragma("unroll") for (int m = 0; m < 4; ++m)                             \
        _Pragma("unroll") for (int n = 0; n < 4; ++n)                         \
            acc[(h) * 4 + m][n] = __builtin_amdgcn_mfma_f32_16x16x32_bf16(    \
                afb[m], bfb[n], acc[(h) * 4 + m][n], 0, 0, 0);                \
    __builtin_amdgcn_s_setprio(0)

__global__ void __launch_bounds__(512, 2) gemm_kernel(const u16* __restrict__ A,
                                                      const u16* __restrict__ B,
                                                      const float* __restrict__ bias,
                                                      float* __restrict__ C) {
    __shared__ __align__(16) u16 sA[2][2][BM * 32];  // 64 KB
    __shared__ __align__(16) u16 sB[2][2][BN * 32];  // 64 KB

    const int tid = threadIdx.x;
    const int lane = tid & 63;
    const int wave = tid >> 6;  // 0..7
    const int wr = wave >> 2;   // 0..1 -> 128-row half of C-tile (NR dim)
    const int wc = wave & 3;    // 0..3 -> 64-col quarter of C-tile (M dim)
    const int lrow = lane & 15;
    const int lq = lane >> 4;
    const int oA = ((lq ^ ((lrow >> 1) & 3)) << 3);  // swizzled octet, u16 units

    // XCD-aware bijective swizzle: 512 wg, 8 XCDs, 64 wg per XCD chunk.
    const int flat = blockIdx.y * 16 + blockIdx.x;
    const int swz = (flat & 7) * 64 + (flat >> 3);
    const int bx = swz & 15;   // M tile
    const int by = swz >> 4;   // NR tile
    const int i0 = by * BM;
    const int j0 = bx * BN;

    // Staging: thread writes LDS linearly at 16*tid and 16*(tid+512); the
    // matching slot position is row=(L>>2), stored octet=(L&3); source octet
    // pre-swizzled. olog is identical for both loads (row1=row0+128, 128/2%4==0).
    const int srow0 = tid >> 2;  // 0..127
    const int olog = (tid & 3) ^ ((srow0 >> 1) & 3);
    const int aoff0 = (i0 + srow0) * K_DIM + olog * 8;
    const int aoff1 = aoff0 + 128 * K_DIM;
    const int boff0 = (j0 + srow0) * K_DIM + olog * 8;
    const int boff1 = boff0 + 128 * K_DIM;
    const int lds_l0 = tid * 8;          // u16 units
    const int lds_l1 = (tid + 512) * 8;

    auto stage = [&](const u16* base, int off0, int off1, u16* slot, int kb) {
        gld_lds16(base + off0 + kb, slot + lds_l0);
        gld_lds16(base + off1 + kb, slot + lds_l1);
    };

    const f32x4 vzero = {0.f, 0.f, 0.f, 0.f};
    f32x4 acc[8][4];
#pragma unroll
    for (int a = 0; a < 8; a++)
#pragma unroll
        for (int b = 0; b < 4; b++) acc[a][b] = vzero;

    // Prologue: 6 slot stages (12 loads); vm4 -> stages 1-2 (0.Aa, 0.Ba)
    // landed; barrier makes that collective for the pre-loop issues.
    stage(A, aoff0, aoff1, sA[0][0], 0);    // 0.Aalpha
    stage(B, boff0, boff1, sB[0][0], 0);    // 0.Balpha
    stage(A, aoff0, aoff1, sA[0][1], 32);   // 0.Abeta
    stage(B, boff0, boff1, sB[0][1], 32);   // 0.Bbeta
    stage(A, aoff0, aoff1, sA[1][0], 64);   // 1.Aalpha
    stage(B, boff0, boff1, sB[1][0], 64);   // 1.Balpha
    WAIT_VM4;
    FENCE;
    __builtin_amdgcn_s_barrier();

    bf16x8 afA[4], afB[4], bfA[4], bfB[4];
    ISSUE_A(afA, 0, 0, 0);  // t0.P1 operands
    ISSUE_B(bfA, 0, 0);
    FENCE;

    for (int kt = 0; kt < K_DIM / BK; ++kt) {
        const int bufv = kt & 1;
        const int kb1 = (kt + 1 < 64 ? kt + 1 : 63) * 64 + 32;  // clamped tail
        const int kb2 = (kt + 2 < 64 ? kt + 2 : 63) * 64;

        // ---- P1: prefetch (ks0,h1); MFMA(h0) on afA,bfA ----
        ISSUE_A(afB, bufv, 0, 1);
        stage(A, aoff0, aoff1, sA[bufv ^ 1][1], kb1);
        SB0;
        MFMA_HALF(0, afA, bfA);
        WAIT_VM6;
        FENCE;
        __builtin_amdgcn_s_barrier();

        // ---- P2: prefetch (ks1,h0)+(B ks1); MFMA(h1) on afB,bfA ----
        ISSUE_A(afA, bufv, 1, 0);
        ISSUE_B(bfB, bufv, 1);
        stage(B, boff0, boff1, sB[bufv ^ 1][1], kb1);
        SB0;
        MFMA_HALF(1, afB, bfA);
        FENCE;
        __builtin_amdgcn_s_barrier();

        // ---- P3: prefetch (ks1,h1); MFMA(h0) on afA,bfB ----
        ISSUE_A(afB, bufv, 1, 1);
        stage(A, aoff0, aoff1, sA[bufv][0], kb2);
        SB0;
        MFMA_HALF(0, afA, bfB);
        WAIT_VM6;
        FENCE;
        __builtin_amdgcn_s_barrier();

        // ---- P4: prefetch next tile (ks0,h0)+(B ks0); MFMA(h1) on afB,bfB ----
        ISSUE_A(afA, bufv ^ 1, 0, 0);
        ISSUE_B(bfA, bufv ^ 1, 0);
        stage(B, boff0, boff1, sB[bufv][0], kb2);
        SB0;
        MFMA_HALF(1, afB, bfB);
        FENCE;
        __builtin_amdgcn_s_barrier();
    }

    // Epilogue: same fragment->C mapping as the harness-verified 128^2 kernel.
#pragma unroll
    for (int ni = 0; ni < 4; ++ni) {
        long j = j0 + wc * 64 + ni * 16 + lrow;
        float bv = bias[j];
#pragma unroll
        for (int mi = 0; mi < 8; ++mi) {
            long ib = i0 + wr * 128 + mi * 16 + lq * 4;
#pragma unroll
            for (int r = 0; r < 4; ++r) {
                C[(ib + r) * M_DIM + j] = acc[mi][ni][r] + bv;
            }
        }
    }
}

extern "C" void kernel_launch(void* const* d_in, const int* in_sizes, int n_in,
                              void* d_out, int out_size, void* d_ws, size_t ws_size,
                              hipStream_t stream) {
    const float* x = (const float*)d_in[0];
    const float* dna = (const float*)d_in[1];
    const float* bias = (const float*)d_in[2];
    const int* hd = (const int*)d_in[3];
    float* out = (float*)d_out;

    double* sums = (double*)d_ws;                                   // 16 B
    u16* W = (u16*)((char*)d_ws + 256);                             // 32 MB bf16
    u16* Xb = (u16*)((char*)d_ws + 256 + (size_t)TOTAL_ELEMS * 2);  // 64 MB bf16

    hipMemsetAsync(d_ws, 0, 256, stream);
    reduce_kernel<<<dim3(1024), dim3(256), 0, stream>>>(dna, sums);
    build_w_kernel<<<dim3(2048), dim3(256), 0, stream>>>(hd, dna, sums, W);
    convert_x_kernel<<<dim3((NR_DIM * K_DIM) / (256 * 8)), dim3(256), 0, stream>>>(x, Xb);
    gemm_kernel<<<dim3(M_DIM / BN, NR_DIM / BM), dim3(512), 0, stream>>>(Xb, W, bias, out);
}

// Round 5
// 539.819 us; speedup vs baseline: 1.1313x; 1.0649x over previous
//
#include <hip/hip_runtime.h>

// x [4,2048,4096] f32, dna [6] f32, bias [4096] f32, hd [4096,4096] i32,
// out [4,2048,4096] f32. Internally W and X are cast to bf16 for the MFMA GEMM.
#define M_DIM 4096
#define K_DIM 4096
#define NR_DIM 8192
#define TOTAL_ELEMS (M_DIM * K_DIM)

typedef unsigned short u16;
typedef unsigned int u32;
typedef __bf16 bf16x8 __attribute__((ext_vector_type(8)));
typedef float f32x4 __attribute__((ext_vector_type(4)));
typedef u16 u16x8 __attribute__((ext_vector_type(8)));

__device__ __forceinline__ u16 f2b(float f) {
    u32 v;
    __builtin_memcpy(&v, &f, sizeof(v));
    v += 0x7FFFu + ((v >> 16) & 1u);  // round-to-nearest-even
    return (u16)(v >> 16);
}

// Inline |sin|,|cos| via Cody-Waite + minimax polys. Signs are irrelevant
// downstream (fabs), so quadrant handling is a parity swap only.
__device__ __forceinline__ void abs_sincos(float ang, float* s, float* c) {
    float q = rintf(ang * 0.636619772f);
    float r1 = fmaf(q, -1.57079637e+00f, ang);
    float r = fmaf(q, 4.37113883e-08f, r1);
    float r2 = r * r;
    float ts = fmaf(r2, -1.9840874e-04f, 8.3333310e-03f);
    ts = fmaf(r2, ts, -1.6666667e-01f);
    float sp = fmaf(r * r2, ts, r);
    float tc = fmaf(r2, -1.3888378e-03f, 4.1666638e-02f);
    tc = fmaf(r2, tc, -5.0e-01f);
    float cp = fmaf(r2, tc, 1.0f);
    bool sw = (((int)q) & 1) != 0;
    *s = sw ? cp : sp;
    *c = sw ? sp : cp;
}

// FAST path, valid when a==b==1, n1==n2==n3==0.5 (the actual dna):
// r = 1 / (sqrt|cos| + sqrt|sin|)^2. base in [1, 1.68] — no singularity.
__device__ __forceinline__ float compute_r_fast(int d, float c_ang) {
    float s, c;
    abs_sincos((float)d * c_ang, &s, &c);
    float base = __builtin_amdgcn_sqrtf(fabsf(c)) + __builtin_amdgcn_sqrtf(fabsf(s));
    return __builtin_amdgcn_rcpf(base * base);
}

// GENERIC path for arbitrary dna (powf etc.) — wave-uniform-selected, cold.
__device__ __noinline__ float compute_r_gen(int d, float c_ang, float inv_a,
                                            float inv_b, float n2, float n3, float e) {
    float s, c;
    abs_sincos((float)d * c_ang, &s, &c);
    float ca = fabsf(c) * fabsf(inv_a);
    float sb = fabsf(s) * fabsf(inv_b);
    float t1 = (n2 == 0.5f) ? sqrtf(ca) : ((n2 == 1.0f) ? ca : powf(ca, n2));
    float t2 = (n3 == 0.5f) ? sqrtf(sb) : ((n3 == 1.0f) ? sb : powf(sb, n3));
    float base = t1 + t2;
    if (e == -2.0f) { float ib = __builtin_amdgcn_rcpf(base); return ib * ib; }
    if (e == -1.0f) return __builtin_amdgcn_rcpf(base);
    return powf(base, e);
}

__device__ __forceinline__ bool dna_is_fast(const float* p) {
    return (p[1] == 1.0f) & (p[2] == 1.0f) & (p[3] == 0.5f) &
           (p[4] == 0.5f) & (p[5] == 0.5f);
}

// Kernel 1: sum / sum-of-squares of r (hd is a bijection onto [0,2^24)).
__global__ void __launch_bounds__(256) reduce_kernel(const float* __restrict__ dna,
                                                     double* __restrict__ sums) {
    float p[6];
#pragma unroll
    for (int i = 0; i < 6; i++) p[i] = dna[i];
    float c_ang = (float)((double)p[0] * 6.283185307179586 / 67108864.0);

    double s = 0.0, s2 = 0.0;
    int idx = blockIdx.x * blockDim.x + threadIdx.x;
    int stride = gridDim.x * blockDim.x;
    if (dna_is_fast(p)) {
        for (int d = idx; d < TOTAL_ELEMS; d += stride) {
            float r = compute_r_fast(d, c_ang);
            s += (double)r;
            s2 += (double)r * (double)r;
        }
    } else {
        float inv_a = 1.0f / p[1], inv_b = 1.0f / p[2], e = -1.0f / p[3];
        for (int d = idx; d < TOTAL_ELEMS; d += stride) {
            float r = compute_r_gen(d, c_ang, inv_a, inv_b, p[4], p[5], e);
            s += (double)r;
            s2 += (double)r * (double)r;
        }
    }
#pragma unroll
    for (int off = 32; off > 0; off >>= 1) {
        s += __shfl_down(s, off);
        s2 += __shfl_down(s2, off);
    }
    __shared__ double ls[4], ls2[4];
    int lane = threadIdx.x & 63, w = threadIdx.x >> 6;
    if (lane == 0) { ls[w] = s; ls2[w] = s2; }
    __syncthreads();
    if (threadIdx.x == 0) {
        atomicAdd(&sums[0], ls[0] + ls[1] + ls[2] + ls[3]);
        atomicAdd(&sums[1], ls2[0] + ls2[1] + ls2[2] + ls2[3]);
    }
}

// Kernel 2: W[m,k] = (r - mean)/(std_ddof1 + 1e-9) * (1/sqrt(K)), stored bf16.
__global__ void __launch_bounds__(256) build_w_kernel(const int* __restrict__ hd,
                                                      const float* __restrict__ dna,
                                                      const double* __restrict__ sums,
                                                      u16* __restrict__ W) {
    float p[6];
#pragma unroll
    for (int i = 0; i < 6; i++) p[i] = dna[i];
    float c_ang = (float)((double)p[0] * 6.283185307179586 / 67108864.0);

    const double cnt = (double)TOTAL_ELEMS;
    double sum = sums[0], sumsq = sums[1];
    float meanf = (float)(sum / cnt);
    float stdf = (float)sqrt((sumsq - sum * sum / cnt) / (cnt - 1.0));
    float sc = 0.015625f / (stdf + 1e-9f);  // fold 1/sqrt(4096)

    int idx = blockIdx.x * blockDim.x + threadIdx.x;
    int stride = gridDim.x * blockDim.x;
    if (dna_is_fast(p)) {
        for (int i = idx * 4; i < TOTAL_ELEMS; i += stride * 4) {
            int4 d4 = *(const int4*)(hd + i);
            ushort4 o;
            o.x = f2b((compute_r_fast(d4.x, c_ang) - meanf) * sc);
            o.y = f2b((compute_r_fast(d4.y, c_ang) - meanf) * sc);
            o.z = f2b((compute_r_fast(d4.z, c_ang) - meanf) * sc);
            o.w = f2b((compute_r_fast(d4.w, c_ang) - meanf) * sc);
            *(ushort4*)(W + i) = o;
        }
    } else {
        float inv_a = 1.0f / p[1], inv_b = 1.0f / p[2], e = -1.0f / p[3];
        for (int i = idx * 4; i < TOTAL_ELEMS; i += stride * 4) {
            int4 d4 = *(const int4*)(hd + i);
            ushort4 o;
            o.x = f2b((compute_r_gen(d4.x, c_ang, inv_a, inv_b, p[4], p[5], e) - meanf) * sc);
            o.y = f2b((compute_r_gen(d4.y, c_ang, inv_a, inv_b, p[4], p[5], e) - meanf) * sc);
            o.z = f2b((compute_r_gen(d4.z, c_ang, inv_a, inv_b, p[4], p[5], e) - meanf) * sc);
            o.w = f2b((compute_r_gen(d4.w, c_ang, inv_a, inv_b, p[4], p[5], e) - meanf) * sc);
            *(ushort4*)(W + i) = o;
        }
    }
}

// Kernel 3: x f32 -> bf16 (8 elements/thread).
__global__ void __launch_bounds__(256) convert_x_kernel(const float* __restrict__ x,
                                                        u16* __restrict__ xb) {
    int i = (blockIdx.x * blockDim.x + threadIdx.x) * 8;
    const float4* xv = (const float4*)(x + i);
    float4 a = xv[0], b = xv[1];
    u16x8 o;
    o[0] = f2b(a.x); o[1] = f2b(a.y); o[2] = f2b(a.z); o[3] = f2b(a.w);
    o[4] = f2b(b.x); o[5] = f2b(b.y); o[6] = f2b(b.z); o[7] = f2b(b.w);
    *(u16x8*)(xb + i) = o;
}

// ---------------- GEMM: C[NR,M] = X[NR,K] * W[M,K]^T -----------------------
// Round 5: TWO phases per K-tile (32-MFMA clusters, 2 barriers + 2 vm-waits
// per K-tile), full register prefetch. Rationale: r3->r4 showed barrier/phase
// count is the live lever (8->4 barriers/K-tile = -31 us); at 1 block/CU
// (256^2 tile forces it via VGPR+LDS) exposed sync latency dominates, so
// halve the sync points again and double the MFMA cluster width.
//
// Banks (all statically indexed): afA/afB = A(ks0) h0/h1; afC/afD = A(ks1)
// h0/h1; bfA = B(ks0); bfB = B(ks1). acc 128 VGPR. Total ~240 VGPR.
//
// Phase alpha of tile t (parity p=t&1): compute ks0, prefetch ks1, stage
//   (t+1).ks1 (A+B). Phase beta: compute ks1, prefetch (t+1).ks0, stage
//   (t+2).ks0 (A+B).
//
// Wait discipline — re-derived, NOT inherited from r4 (vm8 there would be
// WRONG here): stage->read distance is 2 phases for every slot, and each
// phase issues 4 DMA loads, so at each phase end we must have "everything
// older than this phase" landed => WAIT vmcnt(4) (leaves exactly the current
// phase's 4 loads in flight). vm8 would leave the previous phase's stages
// outstanding — and those are exactly the slots read next phase.
//
// Safety proofs:
//  RAW: t.alpha reads A/B(t).ks1 staged at (t-1).alpha: (t-1).beta-end vm4
//    leaves only (t-1).beta's 4 loads => (t-1).alpha's landed; barrier makes
//    it collective. t.beta reads A/B(t+1).ks0 staged at (t-1).beta: t.alpha-
//    end vm4 => landed. Pre-loop reads (t0.ks0) covered by prologue vm4.
//  WAW: alpha stages sA/sB[p^1][1] whose previous contents' reads were
//    issued at (t-1).alpha and CONSUMED by (t-1).beta's MFMA (compiler lgkm)
//    before the (t-1).beta-end barrier => >=1 full barrier before overwrite.
//    beta stages sA/sB[p][0]: previous reads consumed by t.alpha's MFMA
//    before the t.alpha-end barrier. OK.
//  Prologue: 6 slot-stages in order {A0k0,B0k0,A0k1,B0k1,A1k0,B1k0}; vm4 =>
//    first 8 loads (A0k0,B0k0,A0k1,B0k1) landed; barrier; pre-loop prefetch
//    reads A0k0/B0k0. t0.alpha-end vm4 => A1k0,B1k0 landed for t0.beta. OK.
//  Tail: stages CLAMPED (tile 63) into dead/already-consumed slots; final
//    prefetches read dead banks. vmcnt stays steady-state exact.
#define BM 256
#define BN 256
#define BK 64

__device__ __forceinline__ void gld_lds16(const u16* g, u16* l) {
    __builtin_amdgcn_global_load_lds(
        (const __attribute__((address_space(1))) void*)g,
        (__attribute__((address_space(3))) void*)l,
        16, 0, 0);
}

#define FENCE asm volatile("" ::: "memory")
#define WAIT_VM4 asm volatile("s_waitcnt vmcnt(4)" ::: "memory")
#define SB0 __builtin_amdgcn_sched_barrier(0)

// Issue 4 A-fragment ds_reads into bank `dst` (rows h*64..h*64+63 of this
// wave's 128-row half; k-slice ks of buffer bufv).
#define ISSUE_A(dst, bufv, ks, h)                                             \
    _Pragma("unroll") for (int m = 0; m < 4; ++m) {                           \
        int row = wr * 128 + ((h) * 4 + m) * 16 + lrow;                       \
        dst[m] = *(const bf16x8*)(&sA[bufv][ks][row * 32 + oA]);              \
    }

// Issue 4 B-fragment ds_reads into bank `dst` (this wave's 64-col quarter).
#define ISSUE_B(dst, bufv, ks)                                                \
    _Pragma("unroll") for (int n = 0; n < 4; ++n) {                           \
        int row = wc * 64 + n * 16 + lrow;                                    \
        dst[n] = *(const bf16x8*)(&sB[bufv][ks][row * 32 + oA]);              \
    }

// 16 MFMAs updating acc rows h*4..h*4+3 from one A bank x one B bank.
#define MFMA_HALF(h, afb, bfb)                                                \
    _Pragma("unroll") for (int m = 0; m < 4; ++m)                             \
        _Pragma("unroll") for (int n = 0; n < 4; ++n)                         \
            acc[(h) * 4 + m][n] = __builtin_amdgcn_mfma_f32_16x16x32_bf16(    \
                afb[m], bfb[n], acc[(h) * 4 + m][n], 0, 0, 0)

__global__ void __launch_bounds__(512, 2) gemm_kernel(const u16* __restrict__ A,
                                                      const u16* __restrict__ B,
                                                      const float* __restrict__ bias,
                                                      float* __restrict__ C) {
    __shared__ __align__(16) u16 sA[2][2][BM * 32];  // 64 KB
    __shared__ __align__(16) u16 sB[2][2][BN * 32];  // 64 KB

    const int tid = threadIdx.x;
    const int lane = tid & 63;
    const int wave = tid >> 6;  // 0..7
    const int wr = wave >> 2;   // 0..1 -> 128-row half of C-tile (NR dim)
    const int wc = wave & 3;    // 0..3 -> 64-col quarter of C-tile (M dim)
    const int lrow = lane & 15;
    const int lq = lane >> 4;
    const int oA = ((lq ^ ((lrow >> 1) & 3)) << 3);  // swizzled octet, u16 units

    // XCD-aware bijective swizzle: 512 wg, 8 XCDs, 64 wg per XCD chunk.
    const int flat = blockIdx.y * 16 + blockIdx.x;
    const int swz = (flat & 7) * 64 + (flat >> 3);
    const int bx = swz & 15;   // M tile
    const int by = swz >> 4;   // NR tile
    const int i0 = by * BM;
    const int j0 = bx * BN;

    // Staging: thread writes LDS linearly at 16*tid and 16*(tid+512); the
    // matching slot position is row=(L>>2), stored octet=(L&3); source octet
    // pre-swizzled. olog is identical for both loads (row1=row0+128, 128/2%4==0).
    const int srow0 = tid >> 2;  // 0..127
    const int olog = (tid & 3) ^ ((srow0 >> 1) & 3);
    const int aoff0 = (i0 + srow0) * K_DIM + olog * 8;
    const int aoff1 = aoff0 + 128 * K_DIM;
    const int boff0 = (j0 + srow0) * K_DIM + olog * 8;
    const int boff1 = boff0 + 128 * K_DIM;
    const int lds_l0 = tid * 8;          // u16 units
    const int lds_l1 = (tid + 512) * 8;

    auto stage = [&](const u16* base, int off0, int off1, u16* slot, int kb) {
        gld_lds16(base + off0 + kb, slot + lds_l0);
        gld_lds16(base + off1 + kb, slot + lds_l1);
    };

    const f32x4 vzero = {0.f, 0.f, 0.f, 0.f};
    f32x4 acc[8][4];
#pragma unroll
    for (int a = 0; a < 8; a++)
#pragma unroll
        for (int b = 0; b < 4; b++) acc[a][b] = vzero;

    // Prologue: 6 slot stages (12 loads); vm4 -> first 4 slots landed.
    stage(A, aoff0, aoff1, sA[0][0], 0);    // 0.A ks0
    stage(B, boff0, boff1, sB[0][0], 0);    // 0.B ks0
    stage(A, aoff0, aoff1, sA[0][1], 32);   // 0.A ks1
    stage(B, boff0, boff1, sB[0][1], 32);   // 0.B ks1
    stage(A, aoff0, aoff1, sA[1][0], 64);   // 1.A ks0
    stage(B, boff0, boff1, sB[1][0], 64);   // 1.B ks0
    WAIT_VM4;
    FENCE;
    __builtin_amdgcn_s_barrier();

    bf16x8 afA[4], afB[4], afC[4], afD[4], bfA[4], bfB[4];
    // Pre-loop prefetch: t0 ks0 operands (both halves + B).
    ISSUE_A(afA, 0, 0, 0);
    ISSUE_A(afB, 0, 0, 1);
    ISSUE_B(bfA, 0, 0);
    FENCE;

    for (int kt = 0; kt < K_DIM / BK; ++kt) {
        const int p = kt & 1;
        const int kb1 = (kt + 1 < 64 ? kt + 1 : 63) * 64 + 32;  // (t+1).ks1, clamped
        const int kb2 = (kt + 2 < 64 ? kt + 2 : 63) * 64;       // (t+2).ks0, clamped

        // ---- phase alpha: compute ks0; prefetch ks1; stage (t+1).ks1 ----
        ISSUE_A(afC, p, 1, 0);
        ISSUE_A(afD, p, 1, 1);
        ISSUE_B(bfB, p, 1);
        stage(A, aoff0, aoff1, sA[p ^ 1][1], kb1);
        stage(B, boff0, boff1, sB[p ^ 1][1], kb1);
        SB0;
        __builtin_amdgcn_s_setprio(1);
        MFMA_HALF(0, afA, bfA);
        MFMA_HALF(1, afB, bfA);
        __builtin_amdgcn_s_setprio(0);
        WAIT_VM4;
        FENCE;
        __builtin_amdgcn_s_barrier();

        // ---- phase beta: compute ks1; prefetch (t+1).ks0; stage (t+2).ks0 ----
        ISSUE_A(afA, p ^ 1, 0, 0);
        ISSUE_A(afB, p ^ 1, 0, 1);
        ISSUE_B(bfA, p ^ 1, 0);
        stage(A, aoff0, aoff1, sA[p][0], kb2);
        stage(B, boff0, boff1, sB[p][0], kb2);
        SB0;
        __builtin_amdgcn_s_setprio(1);
        MFMA_HALF(0, afC, bfB);
        MFMA_HALF(1, afD, bfB);
        __builtin_amdgcn_s_setprio(0);
        WAIT_VM4;
        FENCE;
        __builtin_amdgcn_s_barrier();
    }

    // Epilogue: same fragment->C mapping as the harness-verified 128^2 kernel.
#pragma unroll
    for (int ni = 0; ni < 4; ++ni) {
        long j = j0 + wc * 64 + ni * 16 + lrow;
        float bv = bias[j];
#pragma unroll
        for (int mi = 0; mi < 8; ++mi) {
            long ib = i0 + wr * 128 + mi * 16 + lq * 4;
#pragma unroll
            for (int r = 0; r < 4; ++r) {
                C[(ib + r) * M_DIM + j] = acc[mi][ni][r] + bv;
            }
        }
    }
}

extern "C" void kernel_launch(void* const* d_in, const int* in_sizes, int n_in,
                              void* d_out, int out_size, void* d_ws, size_t ws_size,
                              hipStream_t stream) {
    const float* x = (const float*)d_in[0];
    const float* dna = (const float*)d_in[1];
    const float* bias = (const float*)d_in[2];
    const int* hd = (const int*)d_in[3];
    float* out = (float*)d_out;

    double* sums = (double*)d_ws;                                   // 16 B
    u16* W = (u16*)((char*)d_ws + 256);                             // 32 MB bf16
    u16* Xb = (u16*)((char*)d_ws + 256 + (size_t)TOTAL_ELEMS * 2);  // 64 MB bf16

    hipMemsetAsync(d_ws, 0, 256, stream);
    reduce_kernel<<<dim3(1024), dim3(256), 0, stream>>>(dna, sums);
    build_w_kernel<<<dim3(2048), dim3(256), 0, stream>>>(hd, dna, sums, W);
    convert_x_kernel<<<dim3((NR_DIM * K_DIM) / (256 * 8)), dim3(256), 0, stream>>>(x, Xb);
    gemm_kernel<<<dim3(M_DIM / BN, NR_DIM / BM), dim3(512), 0, stream>>>(Xb, W, bias, out);
}